// Round 4
// baseline (171.610 us; speedup 1.0000x reference)
//
#include <hip/hip_runtime.h>
#include <math.h>

// Problem shape (fixed by setup_inputs)
#define BATCH 32
#define HH 768
#define WW 768

typedef float v4f __attribute__((ext_vector_type(4)));

// ---------------------------------------------------------------------------
// Kernel 1: block = (b, ri, quarter) covering 24 rows x 768 cols.
// 3 iterations of 8-row chunks, double-buffered: 12 dwordx4 (6 pred + 6 gt)
// issued for chunk i+1 while chunk i is consumed; s_waitcnt vmcnt(12) between.
// 32-lane group g owns column stripe g (96 floats / 24 float4).
// ---------------------------------------------------------------------------
__global__ __launch_bounds__(256) void region_reduce(
    const float* __restrict__ pred, const float* __restrict__ gt,
    float* __restrict__ sq_out, float* __restrict__ dws)
{
    const int bid = blockIdx.x;          // (b*8 + ri)*4 + qt
    const int b   = bid >> 5;
    const int ri  = (bid >> 2) & 7;
    const int qt  = bid & 3;
    const size_t base = (size_t)b * (HH * WW) + (size_t)(ri * 96 + qt * 24) * WW;

    const int t = threadIdx.x;
    const int g = t >> 5;       // column stripe 0..7
    const int l = t & 31;

    const float* pb = pred + base;   // block-uniform -> SGPR pair
    const float* gb = gt   + base;

    // 8-row chunk = 8 x 24 float4 per stripe; lane l handles q = l + 32k, k<6
    unsigned off0[6];
    #pragma unroll
    for (int k = 0; k < 6; ++k) {
        const int q = l + 32 * k;        // 0..191
        const int row = q / 24;          // 0..7
        const int c   = q - row * 24;    // 0..23
        off0[k] = (unsigned)((row * WW + g * 96 + c * 4) * sizeof(float));
    }

    v4f P[2][6], G[2][6];
    float sq = 0.f, ds = 0.f;

#define ISSUE(S, DISP)                                                        \
    {                                                                         \
        _Pragma("unroll") for (int k = 0; k < 6; ++k) {                       \
            asm volatile("global_load_dwordx4 %0, %1, %2"                     \
                         : "=&v"(P[S][k]) : "v"(off0[k] + (DISP)), "s"(pb));  \
        }                                                                     \
        _Pragma("unroll") for (int k = 0; k < 6; ++k) {                       \
            asm volatile("global_load_dwordx4 %0, %1, %2"                     \
                         : "=&v"(G[S][k]) : "v"(off0[k] + (DISP)), "s"(gb));  \
        }                                                                     \
    }

#define WAITN(S, N)                                                           \
    asm volatile("s_waitcnt vmcnt(" #N ")"                                    \
                 : "+v"(P[S][0]), "+v"(P[S][1]), "+v"(P[S][2]),               \
                   "+v"(P[S][3]), "+v"(P[S][4]), "+v"(P[S][5]),               \
                   "+v"(G[S][0]), "+v"(G[S][1]), "+v"(G[S][2]),               \
                   "+v"(G[S][3]), "+v"(G[S][4]), "+v"(G[S][5]) :: "memory");

#define CONSUME(S)                                                            \
    {                                                                         \
        _Pragma("unroll") for (int k = 0; k < 6; ++k) {                       \
            const float dx = P[S][k][0] - G[S][k][0];                         \
            const float dy = P[S][k][1] - G[S][k][1];                         \
            const float dz = P[S][k][2] - G[S][k][2];                         \
            const float dw = P[S][k][3] - G[S][k][3];                         \
            sq += (dx * dx + dy * dy) + (dz * dz + dw * dw);                  \
            ds += (dx + dy) + (dz + dw);                                      \
        }                                                                     \
    }

    // chunk byte stride = 8 rows * 768 cols * 4 B = 24576
    ISSUE(0, 0u)
    ISSUE(1, 24576u)
    WAITN(0, 12)
    CONSUME(0)
    ISSUE(0, 49152u)
    WAITN(1, 12)
    CONSUME(1)
    WAITN(0, 0)
    CONSUME(0)

#undef ISSUE
#undef WAITN
#undef CONSUME

    // ds: reduce within the 32-lane group (stripe-local)
    #pragma unroll
    for (int o = 16; o > 0; o >>= 1) ds += __shfl_down(ds, o, 64);
    // sq: reduce across the full 64-lane wave
    #pragma unroll
    for (int o = 32; o > 0; o >>= 1) sq += __shfl_down(sq, o, 64);

    if (l == 0) {
        const int r = ((b << 3) + ri) * 8 + g;   // region id 0..2047
        dws[r * 4 + qt] = ds;
    }

    __shared__ float lsq[4];
    const int wave = t >> 6;
    if ((t & 63) == 0) lsq[wave] = sq;
    __syncthreads();
    if (t == 0) sq_out[bid] = (lsq[0] + lsq[1]) + (lsq[2] + lsq[3]);
}

// ---------------------------------------------------------------------------
// Kernel 2: single block. Aggregates quarter partials -> level-3 regions,
// builds levels 2/1, count loss, domain CE, final weighted sum.
// ---------------------------------------------------------------------------
__global__ __launch_bounds__(256) void finalize(
    const float* __restrict__ sq, const float* __restrict__ dws,
    const float* __restrict__ rgb, const float* __restrict__ th,
    float* __restrict__ out)
{
    __shared__ float d[2048];        // level-3 region diffs (b*64 + ri*8 + rj)
    __shared__ float d2[BATCH * 16];
    __shared__ float d1[BATCH * 4];
    __shared__ float redbuf[4 * 6];
    const int t = threadIdx.x;

    // density partials (1024 floats as 256 float4)
    float s_sq = 0.f;
    {
        const float4 v = ((const float4*)sq)[t];
        s_sq = (v.x + v.y) + (v.z + v.w);
    }

    // level-3 region diffs: sum 4 quarter partials each (one float4)
    float l3 = 0.f;
    #pragma unroll
    for (int k = 0; k < 8; ++k) {
        const int r = t + 256 * k;
        const float4 a = ((const float4*)dws)[r];
        const float v = (a.x + a.y) + (a.z + a.w);
        d[r] = v;
        l3 += fabsf(v);
    }
    __syncthreads();

    // level 2: 32 batches x 16 cells, 2x2 aggregation of level-3
    float l2 = 0.f;
    #pragma unroll
    for (int k = 0; k < 2; ++k) {
        const int i = t + 256 * k;
        const int b = i >> 4, r2 = i & 15;
        const int i2 = r2 >> 2, j2 = r2 & 3;
        const float* db = d + b * 64;
        const float v = (db[(2 * i2) * 8 + 2 * j2]     + db[(2 * i2) * 8 + 2 * j2 + 1])
                      + (db[(2 * i2 + 1) * 8 + 2 * j2] + db[(2 * i2 + 1) * 8 + 2 * j2 + 1]);
        d2[i] = v;
        l2 += fabsf(v);
    }
    __syncthreads();

    // level 1: 32 x 4 cells
    float l1 = 0.f;
    if (t < BATCH * 4) {
        const int b = t >> 2, r1 = t & 3;
        const int i1 = r1 >> 1, j1 = r1 & 1;
        const float* db = d2 + b * 16;
        const float v = (db[(2 * i1) * 4 + 2 * j1]     + db[(2 * i1) * 4 + 2 * j1 + 1])
                      + (db[(2 * i1 + 1) * 4 + 2 * j1] + db[(2 * i1 + 1) * 4 + 2 * j1 + 1]);
        d1[t] = v;
        l1 = fabsf(v);
    }
    __syncthreads();

    // per-batch count diff + domain CE
    float cnt = 0.f, dom = 0.f;
    if (t < BATCH) {
        const float c = (d1[t * 4] + d1[t * 4 + 1]) + (d1[t * 4 + 2] + d1[t * 4 + 3]);
        cnt = fabsf(c);
        const float x0 = rgb[t * 2], x1 = rgb[t * 2 + 1];
        const float mx = fmaxf(x0, x1);
        dom  = (mx + logf(expf(x0 - mx) + expf(x1 - mx))) - x0;
        const float y0 = th[t * 2], y1 = th[t * 2 + 1];
        const float my = fmaxf(y0, y1);
        dom += (my + logf(expf(y0 - my) + expf(y1 - my))) - y1;
    }

    // fused 6-value reduction: wave shuffle, then 4-wave LDS combine
    float vals[6] = {s_sq, l3, l2, l1, cnt, dom};
    #pragma unroll
    for (int off = 32; off > 0; off >>= 1) {
        #pragma unroll
        for (int j = 0; j < 6; ++j) vals[j] += __shfl_down(vals[j], off, 64);
    }
    const int wave = t >> 6;
    if ((t & 63) == 0) {
        #pragma unroll
        for (int j = 0; j < 6; ++j) redbuf[wave * 6 + j] = vals[j];
    }
    __syncthreads();
    if (t == 0) {
        float S[6];
        #pragma unroll
        for (int j = 0; j < 6; ++j)
            S[j] = (redbuf[j] + redbuf[6 + j]) + (redbuf[12 + j] + redbuf[18 + j]);
        const float density  = S[0] / (float)((size_t)BATCH * HH * WW);
        const float count_l  = S[4] / (float)BATCH;
        const float regional = ((S[3] + S[2] + S[1]) / (float)BATCH) / 192.0f;
        const float domain   = S[5] / 64.0f;
        out[0] = 100.0f * density + 0.001f * count_l + 1.0f * regional + 0.5f * domain;
    }
}

extern "C" void kernel_launch(void* const* d_in, const int* in_sizes, int n_in,
                              void* d_out, int out_size, void* d_ws, size_t ws_size,
                              hipStream_t stream) {
    const float* pred = (const float*)d_in[0];
    const float* gt   = (const float*)d_in[1];
    const float* rgb  = (const float*)d_in[2];
    const float* th   = (const float*)d_in[3];
    float* out = (float*)d_out;

    float* sq  = (float*)d_ws;         // [1024] per-block sq partials
    float* dws = sq + 1024;            // [2048 * 4] quarter partials

    region_reduce<<<1024, 256, 0, stream>>>(pred, gt, sq, dws);
    finalize<<<1, 256, 0, stream>>>(sq, dws, rgb, th, out);
}